// Round 2
// baseline (1753.294 us; speedup 1.0000x reference)
//
#include <hip/hip_runtime.h>
#include <math.h>

typedef _Float16 f16;
typedef _Float16 f16x8 __attribute__((ext_vector_type(8)));
typedef float f32x4 __attribute__((ext_vector_type(4)));

#define NSTEP 128
#define FEAT  127
#define BLK_B 16
#define NBLOCK 256
#define NTHREADS 512

__device__ __forceinline__ float sigf(float x) { return 1.0f / (1.0f + __expf(-x)); }
__device__ __forceinline__ float tanh_(float x) { return 1.0f - 2.0f / (1.0f + __expf(2.0f * x)); }

// f16 MFMA B-fragments in d_ws. Segments sel: 0=w_ih0 1=w_hh0 2=w_ih1 3=w_hh1,
// each 65536 halfs. Fragment (sel,wave,gate,ks,lane) is the f16x8 at index
//   sel*8192 + ((wave*4+gate)*4+ks)*64 + lane
// holding W[n][k] with n = gate*128 + wave*16 + (lane&15),
//                     k = ks*32 + (lane>>4)*8 + j   (j = 0..7, contiguous).
__global__ void prep_weights(const float* __restrict__ w_ih0,
                             const float* __restrict__ w_hh0,
                             const float* __restrict__ w_ih1,
                             const float* __restrict__ w_hh1,
                             f16* __restrict__ ws16)
{
    int idx = blockIdx.x * blockDim.x + threadIdx.x;  // 0 .. 262143
    int j    = idx & 7;
    int lane = (idx >> 3) & 63;
    int ks   = (idx >> 9) & 3;
    int gate = (idx >> 11) & 3;
    int wave = (idx >> 13) & 7;
    int sel  = (idx >> 16) & 3;
    int n = gate * 128 + wave * 16 + (lane & 15);
    int k = ks * 32 + (lane >> 4) * 8 + j;
    const float* W = (sel == 0) ? w_ih0 : (sel == 1) ? w_hh0 : (sel == 2) ? w_ih1 : w_hh1;
    ws16[idx] = (f16)W[n * 128 + k];
}

// One block = 16 batch rows, full time loop. 8 waves; wave w owns gate columns
// u in [16w,16w+16) for both layers. w_hh0/w_ih1/w_hh1 fragments live in
// registers (192 VGPRs/lane); only w_ih0 streams from L2 (128 KB hot/XCD).
__global__ __launch_bounds__(NTHREADS, 2) void lstm_main(
    const float* __restrict__ nf,   const float* __restrict__ tgt,
    const float* __restrict__ b_ih0, const float* __restrict__ b_hh0,
    const float* __restrict__ b_ih1, const float* __restrict__ b_hh1,
    const float* __restrict__ w_out, const float* __restrict__ b_out,
    const f16* __restrict__ wfrag,  float* __restrict__ out)
{
    // stride 152 halfs: 16B-aligned rows, row bank-advance 12 dwords -> <=2-way conflicts
    __shared__ f16 xs[2][16][152];
    __shared__ f16 h0s[2][16][152];
    __shared__ f16 h1s[2][16][152];
    __shared__ float outp[8][16];

    const int tid  = threadIdx.x;
    const int wave = tid >> 6;
    const int lane = tid & 63;
    const int col  = lane & 15;
    const int quad = lane >> 4;
    const int b0   = blockIdx.x * BLK_B;
    const int u    = wave * 16 + col;

    for (int i = tid; i < 2 * 16 * 152; i += NTHREADS) {
        (&h0s[0][0][0])[i] = (f16)0.0f;
        (&h1s[0][0][0])[i] = (f16)0.0f;
    }

    float bias0[4], bias1[4];
#pragma unroll
    for (int g = 0; g < 4; ++g) {
        bias0[g] = b_ih0[g * 128 + u] + b_hh0[g * 128 + u];
        bias1[g] = b_ih1[g * 128 + u] + b_hh1[g * 128 + u];
    }
    const float wo_u = w_out[u];
    const float bout = b_out[0];

    const f16x8* wf = (const f16x8*)wfrag;

    // ---- persistent weight fragments (loop-invariant): 48 x f16x8 = 192 VGPRs
    f16x8 whh0[4][4], wih1[4][4], whh1[4][4];
#pragma unroll
    for (int g = 0; g < 4; ++g)
#pragma unroll
        for (int ks = 0; ks < 4; ++ks) {
            const int fi = ((wave * 4 + g) * 4 + ks) * 64 + lane;
            whh0[g][ks] = wf[1 * 8192 + fi];
            wih1[g][ks] = wf[2 * 8192 + fi];
            whh1[g][ks] = wf[3 * 8192 + fi];
        }

    f32x4 c0 = {0.f, 0.f, 0.f, 0.f};
    f32x4 c1 = {0.f, 0.f, 0.f, 0.f};

    // ---- stage x(0): wave w loads rows 2w, 2w+1; k = lane, lane+64
    {
#pragma unroll
        for (int rr = 0; rr < 2; ++rr) {
            const int row = wave * 2 + rr;
            const long gbt = (long)(b0 + row) * NSTEP + 0;
#pragma unroll
            for (int h = 0; h < 2; ++h) {
                const int k = lane + 64 * h;
                float v = (k < FEAT) ? nf[gbt * FEAT + k] : 0.0f;  // cond(0)=0
                xs[0][row][k] = (f16)v;
            }
        }
    }
    __syncthreads();

    for (int t = 0; t < NSTEP; ++t) {
        const int pa = t & 1;
        const int wb = pa ^ 1;
        const int xc = t & 1;
        const int xn_ = xc ^ 1;

        // ---- prefetch x(t+1) into registers (no LDS write yet, no wait needed)
        float xnv[2][2];
#pragma unroll
        for (int rr = 0; rr < 2; ++rr) {
            const int row = wave * 2 + rr;
#pragma unroll
            for (int h = 0; h < 2; ++h) {
                const int k = lane + 64 * h;
                float v = 0.0f;
                if (t + 1 < NSTEP) {
                    const long gbt = (long)(b0 + row) * NSTEP + (t + 1);
                    v = (k < FEAT) ? nf[gbt * FEAT + k]
                                   : tgt[(long)(b0 + row) * NSTEP + t];
                }
                xnv[rr][h] = v;
            }
        }

        // ---- layer 0: gates0 = x@W_ih0^T + h0_prev@W_hh0^T + bias
        f32x4 acc[4];
#pragma unroll
        for (int g = 0; g < 4; ++g)
            acc[g] = (f32x4){bias0[g], bias0[g], bias0[g], bias0[g]};
#pragma unroll
        for (int ks = 0; ks < 4; ++ks) {
            f16x8 a = *(const f16x8*)&xs[xc][col][ks * 32 + quad * 8];
#pragma unroll
            for (int g = 0; g < 4; ++g) {
                f16x8 b = wf[((wave * 4 + g) * 4 + ks) * 64 + lane];  // w_ih0 from L2
                acc[g] = __builtin_amdgcn_mfma_f32_16x16x32_f16(a, b, acc[g], 0, 0, 0);
            }
        }
#pragma unroll
        for (int ks = 0; ks < 4; ++ks) {
            f16x8 a = *(const f16x8*)&h0s[pa][col][ks * 32 + quad * 8];
#pragma unroll
            for (int g = 0; g < 4; ++g)
                acc[g] = __builtin_amdgcn_mfma_f32_16x16x32_f16(a, whh0[g][ks], acc[g], 0, 0, 0);
        }
        float h0n[4];
#pragma unroll
        for (int r = 0; r < 4; ++r) {
            const float ig = sigf(acc[0][r]);
            const float fg = sigf(acc[1][r]);
            const float gg = tanh_(acc[2][r]);
            const float og = sigf(acc[3][r]);
            const float cn = fg * c0[r] + ig * gg;
            c0[r] = cn;
            h0n[r] = og * tanh_(cn);
        }
#pragma unroll
        for (int r = 0; r < 4; ++r)
            h0s[wb][quad * 4 + r][u] = (f16)h0n[r];

        __syncthreads();  // M: h0_new visible

        // ---- layer 1: gates1 = h0_new@W_ih1^T + h1_prev@W_hh1^T + bias
#pragma unroll
        for (int g = 0; g < 4; ++g)
            acc[g] = (f32x4){bias1[g], bias1[g], bias1[g], bias1[g]};
#pragma unroll
        for (int ks = 0; ks < 4; ++ks) {
            f16x8 a = *(const f16x8*)&h0s[wb][col][ks * 32 + quad * 8];
#pragma unroll
            for (int g = 0; g < 4; ++g)
                acc[g] = __builtin_amdgcn_mfma_f32_16x16x32_f16(a, wih1[g][ks], acc[g], 0, 0, 0);
        }
#pragma unroll
        for (int ks = 0; ks < 4; ++ks) {
            f16x8 a = *(const f16x8*)&h1s[pa][col][ks * 32 + quad * 8];
#pragma unroll
            for (int g = 0; g < 4; ++g)
                acc[g] = __builtin_amdgcn_mfma_f32_16x16x32_f16(a, whh1[g][ks], acc[g], 0, 0, 0);
        }
        float h1n[4];
#pragma unroll
        for (int r = 0; r < 4; ++r) {
            const float ig = sigf(acc[0][r]);
            const float fg = sigf(acc[1][r]);
            const float gg = tanh_(acc[2][r]);
            const float og = sigf(acc[3][r]);
            const float cn = fg * c1[r] + ig * gg;
            c1[r] = cn;
            h1n[r] = og * tanh_(cn);
        }
#pragma unroll
        for (int r = 0; r < 4; ++r)
            h1s[wb][quad * 4 + r][u] = (f16)h1n[r];

        // ---- store prefetched x(t+1) into the other xs buffer
#pragma unroll
        for (int rr = 0; rr < 2; ++rr) {
            const int row = wave * 2 + rr;
#pragma unroll
            for (int h = 0; h < 2; ++h)
                xs[xn_][row][lane + 64 * h] = (f16)xnv[rr][h];
        }

        // ---- output partial: sum over this wave's 16 units
        float ps[4];
#pragma unroll
        for (int r = 0; r < 4; ++r) ps[r] = h1n[r] * wo_u;
#pragma unroll
        for (int m = 1; m < 16; m <<= 1) {
#pragma unroll
            for (int r = 0; r < 4; ++r) ps[r] += __shfl_xor(ps[r], m, 64);
        }
        if (col == 0) {
#pragma unroll
            for (int r = 0; r < 4; ++r) outp[wave][quad * 4 + r] = ps[r];
        }

        __syncthreads();  // B: h1_new + xs(t+1) + partials visible

        if (tid < 16) {
            float s = bout;
#pragma unroll
            for (int w = 0; w < 8; ++w) s += outp[w][tid];
            out[(long)(b0 + tid) * NSTEP + t] = sigf(s);
        }
    }
}

extern "C" void kernel_launch(void* const* d_in, const int* in_sizes, int n_in,
                              void* d_out, int out_size, void* d_ws, size_t ws_size,
                              hipStream_t stream)
{
    const float* nf    = (const float*)d_in[0];
    const float* tgt   = (const float*)d_in[1];
    const float* w_ih0 = (const float*)d_in[2];
    const float* w_hh0 = (const float*)d_in[3];
    const float* b_ih0 = (const float*)d_in[4];
    const float* b_hh0 = (const float*)d_in[5];
    const float* w_ih1 = (const float*)d_in[6];
    const float* w_hh1 = (const float*)d_in[7];
    const float* b_ih1 = (const float*)d_in[8];
    const float* b_hh1 = (const float*)d_in[9];
    const float* w_out = (const float*)d_in[10];
    const float* b_out = (const float*)d_in[11];

    f16*   ws16 = (f16*)d_ws;   // 512 KB of f16 weight fragments
    float* out  = (float*)d_out;

    prep_weights<<<1024, 256, 0, stream>>>(w_ih0, w_hh0, w_ih1, w_hh1, ws16);
    lstm_main<<<NBLOCK, NTHREADS, 0, stream>>>(nf, tgt, b_ih0, b_hh0, b_ih1, b_hh1,
                                               w_out, b_out, ws16, out);
}

// Round 3
// 854.822 us; speedup vs baseline: 2.0511x; 2.0511x over previous
//
#include <hip/hip_runtime.h>
#include <math.h>

typedef _Float16 f16;
typedef _Float16 f16x8 __attribute__((ext_vector_type(8)));
typedef float f32x4 __attribute__((ext_vector_type(4)));

#define NSTEP 128
#define FEAT  127
#define BLK_B 16
#define NBLOCK 256
#define NTHREADS 512

__device__ __forceinline__ float sigf(float x) { return 1.0f / (1.0f + __expf(-x)); }
__device__ __forceinline__ float tanh_(float x) { return 1.0f - 2.0f / (1.0f + __expf(2.0f * x)); }

// f16 MFMA B-fragments in d_ws. Segments sel: 0=w_ih0 1=w_hh0 2=w_ih1 3=w_hh1,
// each 65536 halfs. Fragment (sel,wave,gate,ks,lane) = f16x8 at
//   sel*8192 + ((wave*4+gate)*4+ks)*64 + lane
// holding W[n][k], n = gate*128 + wave*16 + (lane&15), k = ks*32 + (lane>>4)*8 + j.
__global__ void prep_weights(const float* __restrict__ w_ih0,
                             const float* __restrict__ w_hh0,
                             const float* __restrict__ w_ih1,
                             const float* __restrict__ w_hh1,
                             f16* __restrict__ ws16)
{
    int idx = blockIdx.x * blockDim.x + threadIdx.x;  // 0 .. 262143
    int j    = idx & 7;
    int lane = (idx >> 3) & 63;
    int ks   = (idx >> 9) & 3;
    int gate = (idx >> 11) & 3;
    int wave = (idx >> 13) & 7;
    int sel  = (idx >> 16) & 3;
    int n = gate * 128 + wave * 16 + (lane & 15);
    int k = ks * 32 + (lane >> 4) * 8 + j;
    const float* W = (sel == 0) ? w_ih0 : (sel == 1) ? w_hh0 : (sel == 2) ? w_ih1 : w_hh1;
    ws16[idx] = (f16)W[n * 128 + k];
}

#define PIN(v) asm volatile("" : "+v"(v))

// ---------------- Phase 1: layer 0 only, h0 sequence -> global (f16) ----------
__global__ __launch_bounds__(NTHREADS, 2) void lstm_l0(
    const float* __restrict__ nf,   const float* __restrict__ tgt,
    const float* __restrict__ b_ih0, const float* __restrict__ b_hh0,
    const f16* __restrict__ wfrag,  f16* __restrict__ h0g)
{
    __shared__ f16 xs[2][16][152];
    __shared__ f16 h0s[2][16][152];

    const int tid  = threadIdx.x;
    const int wave = tid >> 6;
    const int lane = tid & 63;
    const int col  = lane & 15;
    const int quad = lane >> 4;
    const int b0   = blockIdx.x * BLK_B;
    const int u    = wave * 16 + col;

    for (int i = tid; i < 2 * 16 * 152; i += NTHREADS)
        (&h0s[0][0][0])[i] = (f16)0.0f;

    float bias0[4];
#pragma unroll
    for (int g = 0; g < 4; ++g)
        bias0[g] = b_ih0[g * 128 + u] + b_hh0[g * 128 + u];

    const f16x8* wf = (const f16x8*)wfrag;

    // persistent fragments: 32 x f16x8 = 128 VGPRs, pinned so they cannot be re-sunk
    f16x8 wih0[4][4], whh0[4][4];
#pragma unroll
    for (int g = 0; g < 4; ++g)
#pragma unroll
        for (int ks = 0; ks < 4; ++ks) {
            const int fi = ((wave * 4 + g) * 4 + ks) * 64 + lane;
            wih0[g][ks] = wf[0 * 8192 + fi];
            whh0[g][ks] = wf[1 * 8192 + fi];
            PIN(wih0[g][ks]);
            PIN(whh0[g][ks]);
        }

    f32x4 c0 = {0.f, 0.f, 0.f, 0.f};

    // stage x(0)
#pragma unroll
    for (int rr = 0; rr < 2; ++rr) {
        const int row = wave * 2 + rr;
        const long gbt = (long)(b0 + row) * NSTEP;
#pragma unroll
        for (int h = 0; h < 2; ++h) {
            const int k = lane + 64 * h;
            xs[0][row][k] = (f16)((k < FEAT) ? nf[gbt * FEAT + k] : 0.0f);
        }
    }
    __syncthreads();

    for (int t = 0; t < NSTEP; ++t) {
        const int pa = t & 1, wb = pa ^ 1;

        // prefetch x(t+1)
        float xnv[2][2];
#pragma unroll
        for (int rr = 0; rr < 2; ++rr) {
            const int row = wave * 2 + rr;
#pragma unroll
            for (int h = 0; h < 2; ++h) {
                const int k = lane + 64 * h;
                float v = 0.0f;
                if (t + 1 < NSTEP) {
                    const long gbt = (long)(b0 + row) * NSTEP + (t + 1);
                    v = (k < FEAT) ? nf[gbt * FEAT + k]
                                   : tgt[(long)(b0 + row) * NSTEP + t];
                }
                xnv[rr][h] = v;
            }
        }

        f32x4 acc[4];
#pragma unroll
        for (int g = 0; g < 4; ++g)
            acc[g] = (f32x4){bias0[g], bias0[g], bias0[g], bias0[g]};
#pragma unroll
        for (int ks = 0; ks < 4; ++ks) {
            f16x8 a = *(const f16x8*)&xs[pa][col][ks * 32 + quad * 8];
#pragma unroll
            for (int g = 0; g < 4; ++g)
                acc[g] = __builtin_amdgcn_mfma_f32_16x16x32_f16(a, wih0[g][ks], acc[g], 0, 0, 0);
        }
#pragma unroll
        for (int ks = 0; ks < 4; ++ks) {
            f16x8 a = *(const f16x8*)&h0s[pa][col][ks * 32 + quad * 8];
#pragma unroll
            for (int g = 0; g < 4; ++g)
                acc[g] = __builtin_amdgcn_mfma_f32_16x16x32_f16(a, whh0[g][ks], acc[g], 0, 0, 0);
        }

        float h0n[4];
#pragma unroll
        for (int r = 0; r < 4; ++r) {
            const float ig = sigf(acc[0][r]);
            const float fg = sigf(acc[1][r]);
            const float gg = tanh_(acc[2][r]);
            const float og = sigf(acc[3][r]);
            const float cn = fg * c0[r] + ig * gg;
            c0[r] = cn;
            h0n[r] = og * tanh_(cn);
        }
#pragma unroll
        for (int r = 0; r < 4; ++r) {
            h0s[wb][quad * 4 + r][u] = (f16)h0n[r];
            h0g[((long)(b0 + quad * 4 + r) * NSTEP + t) * 128 + u] = (f16)h0n[r];
        }

        // store prefetched x(t+1)
#pragma unroll
        for (int rr = 0; rr < 2; ++rr) {
            const int row = wave * 2 + rr;
#pragma unroll
            for (int h = 0; h < 2; ++h)
                xs[wb][row][lane + 64 * h] = (f16)xnv[rr][h];
        }
        __syncthreads();
    }
}

// ---------------- Phase 2: layer 1 + output ----------------------------------
__global__ __launch_bounds__(NTHREADS, 2) void lstm_l1(
    const f16* __restrict__ h0g,
    const float* __restrict__ b_ih1, const float* __restrict__ b_hh1,
    const float* __restrict__ w_out, const float* __restrict__ b_out,
    const f16* __restrict__ wfrag,  float* __restrict__ out)
{
    __shared__ f16 hx[2][16][152];
    __shared__ f16 h1s[2][16][152];
    __shared__ float outp[2][8][16];

    const int tid  = threadIdx.x;
    const int wave = tid >> 6;
    const int lane = tid & 63;
    const int col  = lane & 15;
    const int quad = lane >> 4;
    const int b0   = blockIdx.x * BLK_B;
    const int u    = wave * 16 + col;

    for (int i = tid; i < 2 * 16 * 152; i += NTHREADS)
        (&h1s[0][0][0])[i] = (f16)0.0f;

    float bias1[4];
#pragma unroll
    for (int g = 0; g < 4; ++g)
        bias1[g] = b_ih1[g * 128 + u] + b_hh1[g * 128 + u];
    const float wo_u = w_out[u];
    const float bout = b_out[0];

    const f16x8* wf = (const f16x8*)wfrag;

    f16x8 wih1[4][4], whh1[4][4];
#pragma unroll
    for (int g = 0; g < 4; ++g)
#pragma unroll
        for (int ks = 0; ks < 4; ++ks) {
            const int fi = ((wave * 4 + g) * 4 + ks) * 64 + lane;
            wih1[g][ks] = wf[2 * 8192 + fi];
            whh1[g][ks] = wf[3 * 8192 + fi];
            PIN(wih1[g][ks]);
            PIN(whh1[g][ks]);
        }

    f32x4 c1 = {0.f, 0.f, 0.f, 0.f};

    // stage h0(0): wave w loads rows 2w,2w+1; lane covers dword `lane` of the 256B row
    {
#pragma unroll
        for (int rr = 0; rr < 2; ++rr) {
            const int row = wave * 2 + rr;
            const unsigned* rp = (const unsigned*)(h0g + ((long)(b0 + row) * NSTEP) * 128);
            *(unsigned*)&hx[0][row][lane * 2] = rp[lane];
        }
    }
    __syncthreads();

    for (int t = 0; t < NSTEP; ++t) {
        const int pa = t & 1, wb = pa ^ 1;

        // prefetch h0(t+1)
        unsigned hnv[2] = {0u, 0u};
        if (t + 1 < NSTEP) {
#pragma unroll
            for (int rr = 0; rr < 2; ++rr) {
                const int row = wave * 2 + rr;
                const unsigned* rp = (const unsigned*)(h0g + ((long)(b0 + row) * NSTEP + (t + 1)) * 128);
                hnv[rr] = rp[lane];
            }
        }

        f32x4 acc[4];
#pragma unroll
        for (int g = 0; g < 4; ++g)
            acc[g] = (f32x4){bias1[g], bias1[g], bias1[g], bias1[g]};
#pragma unroll
        for (int ks = 0; ks < 4; ++ks) {
            f16x8 a = *(const f16x8*)&hx[pa][col][ks * 32 + quad * 8];
#pragma unroll
            for (int g = 0; g < 4; ++g)
                acc[g] = __builtin_amdgcn_mfma_f32_16x16x32_f16(a, wih1[g][ks], acc[g], 0, 0, 0);
        }
#pragma unroll
        for (int ks = 0; ks < 4; ++ks) {
            f16x8 a = *(const f16x8*)&h1s[pa][col][ks * 32 + quad * 8];
#pragma unroll
            for (int g = 0; g < 4; ++g)
                acc[g] = __builtin_amdgcn_mfma_f32_16x16x32_f16(a, whh1[g][ks], acc[g], 0, 0, 0);
        }

        float h1n[4];
#pragma unroll
        for (int r = 0; r < 4; ++r) {
            const float ig = sigf(acc[0][r]);
            const float fg = sigf(acc[1][r]);
            const float gg = tanh_(acc[2][r]);
            const float og = sigf(acc[3][r]);
            const float cn = fg * c1[r] + ig * gg;
            c1[r] = cn;
            h1n[r] = og * tanh_(cn);
        }
#pragma unroll
        for (int r = 0; r < 4; ++r)
            h1s[wb][quad * 4 + r][u] = (f16)h1n[r];

        // stage prefetched h0(t+1)
        if (t + 1 < NSTEP) {
#pragma unroll
            for (int rr = 0; rr < 2; ++rr)
                *(unsigned*)&hx[wb][wave * 2 + rr][lane * 2] = hnv[rr];
        }

        // output partial
        float ps[4];
#pragma unroll
        for (int r = 0; r < 4; ++r) ps[r] = h1n[r] * wo_u;
#pragma unroll
        for (int m = 1; m < 16; m <<= 1) {
#pragma unroll
            for (int r = 0; r < 4; ++r) ps[r] += __shfl_xor(ps[r], m, 64);
        }
        if (col == 0) {
#pragma unroll
            for (int r = 0; r < 4; ++r) outp[pa][wave][quad * 4 + r] = ps[r];
        }

        __syncthreads();

        if (tid < 16) {
            float s = bout;
#pragma unroll
            for (int w = 0; w < 8; ++w) s += outp[pa][w][tid];
            out[(long)(b0 + tid) * NSTEP + t] = sigf(s);
        }
    }
}

// ---------------- Fallback (R2 single-kernel, known-passing) ------------------
__global__ __launch_bounds__(NTHREADS, 2) void lstm_fb(
    const float* __restrict__ nf,   const float* __restrict__ tgt,
    const float* __restrict__ b_ih0, const float* __restrict__ b_hh0,
    const float* __restrict__ b_ih1, const float* __restrict__ b_hh1,
    const float* __restrict__ w_out, const float* __restrict__ b_out,
    const f16* __restrict__ wfrag,  float* __restrict__ out)
{
    __shared__ f16 xs[2][16][152];
    __shared__ f16 h0s[2][16][152];
    __shared__ f16 h1s[2][16][152];
    __shared__ float outp[8][16];

    const int tid  = threadIdx.x;
    const int wave = tid >> 6;
    const int lane = tid & 63;
    const int col  = lane & 15;
    const int quad = lane >> 4;
    const int b0   = blockIdx.x * BLK_B;
    const int u    = wave * 16 + col;

    for (int i = tid; i < 2 * 16 * 152; i += NTHREADS) {
        (&h0s[0][0][0])[i] = (f16)0.0f;
        (&h1s[0][0][0])[i] = (f16)0.0f;
    }
    float bias0[4], bias1[4];
#pragma unroll
    for (int g = 0; g < 4; ++g) {
        bias0[g] = b_ih0[g * 128 + u] + b_hh0[g * 128 + u];
        bias1[g] = b_ih1[g * 128 + u] + b_hh1[g * 128 + u];
    }
    const float wo_u = w_out[u];
    const float bout = b_out[0];
    const f16x8* wf = (const f16x8*)wfrag;

    f32x4 c0 = {0.f, 0.f, 0.f, 0.f};
    f32x4 c1 = {0.f, 0.f, 0.f, 0.f};

#pragma unroll
    for (int rr = 0; rr < 2; ++rr) {
        const int row = wave * 2 + rr;
        const long gbt = (long)(b0 + row) * NSTEP;
#pragma unroll
        for (int h = 0; h < 2; ++h) {
            const int k = lane + 64 * h;
            xs[0][row][k] = (f16)((k < FEAT) ? nf[gbt * FEAT + k] : 0.0f);
        }
    }
    __syncthreads();

    for (int t = 0; t < NSTEP; ++t) {
        const int pa = t & 1, wb = pa ^ 1;
        float xnv[2][2];
#pragma unroll
        for (int rr = 0; rr < 2; ++rr) {
            const int row = wave * 2 + rr;
#pragma unroll
            for (int h = 0; h < 2; ++h) {
                const int k = lane + 64 * h;
                float v = 0.0f;
                if (t + 1 < NSTEP) {
                    const long gbt = (long)(b0 + row) * NSTEP + (t + 1);
                    v = (k < FEAT) ? nf[gbt * FEAT + k] : tgt[(long)(b0 + row) * NSTEP + t];
                }
                xnv[rr][h] = v;
            }
        }
        f32x4 acc[4];
#pragma unroll
        for (int g = 0; g < 4; ++g) acc[g] = (f32x4){bias0[g], bias0[g], bias0[g], bias0[g]};
#pragma unroll
        for (int ks = 0; ks < 4; ++ks) {
            f16x8 a = *(const f16x8*)&xs[pa][col][ks * 32 + quad * 8];
#pragma unroll
            for (int g = 0; g < 4; ++g) {
                f16x8 b = wf[((wave * 4 + g) * 4 + ks) * 64 + lane];
                acc[g] = __builtin_amdgcn_mfma_f32_16x16x32_f16(a, b, acc[g], 0, 0, 0);
            }
        }
#pragma unroll
        for (int ks = 0; ks < 4; ++ks) {
            f16x8 a = *(const f16x8*)&h0s[pa][col][ks * 32 + quad * 8];
#pragma unroll
            for (int g = 0; g < 4; ++g) {
                f16x8 b = wf[1 * 8192 + ((wave * 4 + g) * 4 + ks) * 64 + lane];
                acc[g] = __builtin_amdgcn_mfma_f32_16x16x32_f16(a, b, acc[g], 0, 0, 0);
            }
        }
        float h0n[4];
#pragma unroll
        for (int r = 0; r < 4; ++r) {
            const float ig = sigf(acc[0][r]);
            const float fg = sigf(acc[1][r]);
            const float gg = tanh_(acc[2][r]);
            const float og = sigf(acc[3][r]);
            const float cn = fg * c0[r] + ig * gg;
            c0[r] = cn;
            h0n[r] = og * tanh_(cn);
        }
#pragma unroll
        for (int r = 0; r < 4; ++r) h0s[wb][quad * 4 + r][u] = (f16)h0n[r];
        __syncthreads();

#pragma unroll
        for (int g = 0; g < 4; ++g) acc[g] = (f32x4){bias1[g], bias1[g], bias1[g], bias1[g]};
#pragma unroll
        for (int ks = 0; ks < 4; ++ks) {
            f16x8 a = *(const f16x8*)&h0s[wb][col][ks * 32 + quad * 8];
#pragma unroll
            for (int g = 0; g < 4; ++g) {
                f16x8 b = wf[2 * 8192 + ((wave * 4 + g) * 4 + ks) * 64 + lane];
                acc[g] = __builtin_amdgcn_mfma_f32_16x16x32_f16(a, b, acc[g], 0, 0, 0);
            }
        }
#pragma unroll
        for (int ks = 0; ks < 4; ++ks) {
            f16x8 a = *(const f16x8*)&h1s[pa][col][ks * 32 + quad * 8];
#pragma unroll
            for (int g = 0; g < 4; ++g) {
                f16x8 b = wf[3 * 8192 + ((wave * 4 + g) * 4 + ks) * 64 + lane];
                acc[g] = __builtin_amdgcn_mfma_f32_16x16x32_f16(a, b, acc[g], 0, 0, 0);
            }
        }
        float h1n[4];
#pragma unroll
        for (int r = 0; r < 4; ++r) {
            const float ig = sigf(acc[0][r]);
            const float fg = sigf(acc[1][r]);
            const float gg = tanh_(acc[2][r]);
            const float og = sigf(acc[3][r]);
            const float cn = fg * c1[r] + ig * gg;
            c1[r] = cn;
            h1n[r] = og * tanh_(cn);
        }
#pragma unroll
        for (int r = 0; r < 4; ++r) h1s[wb][quad * 4 + r][u] = (f16)h1n[r];
#pragma unroll
        for (int rr = 0; rr < 2; ++rr) {
            const int row = wave * 2 + rr;
#pragma unroll
            for (int h = 0; h < 2; ++h) xs[wb][row][lane + 64 * h] = (f16)xnv[rr][h];
        }
        float ps[4];
#pragma unroll
        for (int r = 0; r < 4; ++r) ps[r] = h1n[r] * wo_u;
#pragma unroll
        for (int m = 1; m < 16; m <<= 1) {
#pragma unroll
            for (int r = 0; r < 4; ++r) ps[r] += __shfl_xor(ps[r], m, 64);
        }
        if (col == 0) {
#pragma unroll
            for (int r = 0; r < 4; ++r) outp[wave][quad * 4 + r] = ps[r];
        }
        __syncthreads();
        if (tid < 16) {
            float s = bout;
#pragma unroll
            for (int w = 0; w < 8; ++w) s += outp[w][tid];
            out[(long)(b0 + tid) * NSTEP + t] = sigf(s);
        }
    }
}

extern "C" void kernel_launch(void* const* d_in, const int* in_sizes, int n_in,
                              void* d_out, int out_size, void* d_ws, size_t ws_size,
                              hipStream_t stream)
{
    const float* nf    = (const float*)d_in[0];
    const float* tgt   = (const float*)d_in[1];
    const float* w_ih0 = (const float*)d_in[2];
    const float* w_hh0 = (const float*)d_in[3];
    const float* b_ih0 = (const float*)d_in[4];
    const float* b_hh0 = (const float*)d_in[5];
    const float* w_ih1 = (const float*)d_in[6];
    const float* w_hh1 = (const float*)d_in[7];
    const float* b_ih1 = (const float*)d_in[8];
    const float* b_hh1 = (const float*)d_in[9];
    const float* w_out = (const float*)d_in[10];
    const float* b_out = (const float*)d_in[11];

    f16*   ws16 = (f16*)d_ws;                    // 512 KB fragments
    float* out  = (float*)d_out;

    prep_weights<<<1024, 256, 0, stream>>>(w_ih0, w_hh0, w_ih1, w_hh1, ws16);

    const size_t need = 512 * 1024 + (size_t)4096 * 128 * 128 * 2;  // frags + h0seq (f16)
    if (ws_size >= need) {
        f16* h0g = ws16 + 4 * 65536;             // after the 512 KB fragment table
        lstm_l0<<<NBLOCK, NTHREADS, 0, stream>>>(nf, tgt, b_ih0, b_hh0, ws16, h0g);
        lstm_l1<<<NBLOCK, NTHREADS, 0, stream>>>(h0g, b_ih1, b_hh1, w_out, b_out, ws16, out);
    } else {
        lstm_fb<<<NBLOCK, NTHREADS, 0, stream>>>(nf, tgt, b_ih0, b_hh0, b_ih1, b_hh1,
                                                 w_out, b_out, ws16, out);
    }
}